// Round 16
// baseline (7684.538 us; speedup 1.0000x reference)
//
#include <hip/hip_runtime.h>
#include <math.h>

typedef __attribute__((ext_vector_type(8))) short bf16x8;   // 8 bf16 (4 VGPR)
typedef __attribute__((ext_vector_type(4))) float f32x4;    // MFMA C/D

static constexpr int Tt = 1024;
static constexpr int Hh = 512;
static constexpr int Cc = 10;

static constexpr int NXCD = 8;       // XCDs; each runs an independent group
static constexpr int BPX  = 32;      // blocks (CUs) per XCD
static constexpr int UPB  = 16;      // hidden units per block (64 gate rows)
static constexpr int NB   = 16;      // batch rows per XCD (8*16 = 128)
static constexpr int THREADS = 256;  // EXACTLY 4 waves: the 256-VGPR-capable shape
static constexpr int GRID = 256;     // 1 block per CU (85 KB LDS forces it)

// ws bytes: [0,1024) flags[8][32] | [1024,2048) rank counters | pad
//           [4096, +256KB) h_hi[2][8][16][512] bf16 | then h_lo 256KB
static constexpr size_t WS_HHI_B = 4096;
static constexpr size_t WS_HLO_B = 4096 + 262144;

__device__ __forceinline__ unsigned short f2bf(float f) {
    unsigned u = __builtin_bit_cast(unsigned, f);
    return (unsigned short)((u + 0x7FFFu + ((u >> 16) & 1u)) >> 16);   // RNE
}
__device__ __forceinline__ float bf2f(unsigned short h) {
    unsigned u = ((unsigned)h) << 16;
    return __builtin_bit_cast(float, u);
}
__device__ __forceinline__ float dot4(float4 a, float4 b) {
    return a.x * b.x + a.y * b.y + a.z * b.z + a.w * b.w;
}
__device__ __forceinline__ float fsig(float x) {
    const float e = __builtin_amdgcn_exp2f(x * -1.44269504f);
    return __builtin_amdgcn_rcpf(1.0f + e);
}
__device__ __forceinline__ float ftanh(float x) {
    const float e = __builtin_amdgcn_exp2f(x * -2.88539008f);
    return 2.0f * __builtin_amdgcn_rcpf(1.0f + e) - 1.0f;
}

__global__ __launch_bounds__(THREADS, 1)
void lstm_fused(const float* __restrict__ x,
                const float* __restrict__ w_ih,
                const float* __restrict__ w_hh,
                const float* __restrict__ b_ih,
                const float* __restrict__ b_hh,
                const float* __restrict__ w_t,
                const float* __restrict__ w_fc,
                const float* __restrict__ b_fc,
                float* __restrict__ out,
                float* __restrict__ ws)
{
    const int tid  = threadIdx.x;
    const int lane = tid & 63;
    const int wv   = tid >> 6;          // 0..3: wave = gate
    const int frow = lane & 15;         // A row / B batch col
    const int kgrp = lane >> 4;         // 8-elem K group within a 32-K step

    int* flags    = (int*)ws;                 // [xcd*32 + rank]
    int* counters = (int*)ws + 256;           // init-time rank claim
    unsigned short* hg_hi = (unsigned short*)((char*)ws + WS_HHI_B);
    unsigned short* hg_lo = (unsigned short*)((char*)ws + WS_HLO_B);

    // LDS: gbuf 5 KB + REAL 80 KB pad (volatile-touched) = 85 KB -> 1 block/CU
    __shared__ __align__(16) float gbuf[64 * 20];     // [gaterow][batch]
    __shared__ int lds_pad[20480];                    // 80 KB
    int* xchg = lds_pad;

    // volatile store at runtime offset: pad cannot be DCE'd or shrunk
    ((volatile char*)lds_pad)[(size_t)tid * 255] = 0;

    // ---- discover physical XCD, claim a rank ----
    if (tid == 0) {
        int xr;
        asm volatile("s_getreg_b32 %0, hwreg(20, 0, 32)" : "=s"(xr));
        const int xcd = xr & 7;
        xchg[0] = xcd;
        xchg[1] = atomicAdd(&counters[xcd * 32], 1) & 31;
    }
    __syncthreads();
    const int xcd  = xchg[0];
    const int rank = xchg[1];
    __syncthreads();
    const int fbase = xcd * BPX;

    // ---- W fragments into registers: gate wv, 16 kk x (hi,lo) = 128 VGPR ----
    bf16x8 wahi[16], walo[16];
    {
        const float* wr = w_hh + (size_t)(wv * Hh + rank * UPB + frow) * Hh;
        #pragma unroll
        for (int kk = 0; kk < 16; ++kk) {
            const float4* s = (const float4*)(wr + kk * 32 + kgrp * 8);
            const float4 f0 = s[0], f1 = s[1];
            const float f[8] = { f0.x, f0.y, f0.z, f0.w, f1.x, f1.y, f1.z, f1.w };
            bf16x8 vhi, vlo;
            #pragma unroll
            for (int j = 0; j < 8; ++j) {
                const unsigned short hb = f2bf(f[j]);
                vhi[j] = (short)hb;
                vlo[j] = (short)f2bf(f[j] - bf2f(hb));
            }
            // pin: origin becomes opaque -> compiler cannot sink/remat the load
            asm("" : "+v"(vhi), "+v"(vlo));
            wahi[kk] = vhi;
            walo[kk] = vlo;
        }
    }

    // ---- elementwise role: thread -> (u, b) ----
    const int u  = tid & 15;
    const int b_ = tid >> 4;                 // 0..15
    const int gj = rank * UPB + u;
    const int gb = xcd * NB + b_;
    float wih_r[4], bias_r[4];
    #pragma unroll
    for (int g = 0; g < 4; ++g) {
        wih_r[g]  = w_ih[g * Hh + gj];
        bias_r[g] = b_ih[g * Hh + gj] + b_hh[g * Hh + gj];
    }
    float creg = 0.0f;

    // ---- owner role (wave 1, ranks 0..15): one batch row's output chain ----
    const bool owner = (rank < NB);
    const int  gb_own = xcd * NB + rank;
    float S1w[Cc], S2w[Cc], bfc_r[Cc];
    #pragma unroll
    for (int c = 0; c < Cc; ++c) { S1w[c] = 0.f; S2w[c] = 0.f; bfc_r[c] = b_fc[c]; }

    // emit out(tprev) from the h buffer at bh/bl (wave-1 lanes, 64-wide)
    auto emit_out = [&](int tprev, const unsigned short* bh, const unsigned short* bl) {
        const size_t rbase = (size_t)rank * Hh + lane * 8;
        const bf16x8 vh = *(const bf16x8*)(bh + rbase);
        const bf16x8 vl = *(const bf16x8*)(bl + rbase);
        float f[8];
        #pragma unroll
        for (int j = 0; j < 8; ++j)
            f[j] = bf2f((unsigned short)vh[j]) + bf2f((unsigned short)vl[j]);
        const float4 hA = make_float4(f[0], f[1], f[2], f[3]);
        const float4 hB = make_float4(f[4], f[5], f[6], f[7]);
        const float4* wt4 = (const float4*)w_t;
        const float4* wf4 = (const float4*)w_fc;
        float r[12];
        r[0] = dot4(hA, wt4[lane * 2])       + dot4(hB, wt4[lane * 2 + 1]);
        r[1] = dot4(hA, wt4[128 + lane * 2]) + dot4(hB, wt4[128 + lane * 2 + 1]);
        #pragma unroll
        for (int c = 0; c < Cc; ++c)
            r[2 + c] = dot4(hA, wf4[c * 128 + lane * 2])
                     + dot4(hB, wf4[c * 128 + lane * 2 + 1]);
        #pragma unroll
        for (int m = 1; m <= 32; m <<= 1)
            #pragma unroll
            for (int k2 = 0; k2 < 12; ++k2)
                r[k2] += __shfl_xor(r[k2], m, 64);
        if (lane == 0) {
            const float a = r[0], b2 = r[1];
            float* po = out + ((size_t)gb_own * Tt + tprev) * Cc;
            #pragma unroll
            for (int c = 0; c < Cc; ++c) {
                const float hw = r[2 + c];
                po[c] = hw + a * S1w[c] + S2w[c] + bfc_r[c];
                S1w[c] += hw;
                S2w[c] += b2 * hw;
            }
        }
    };

    for (int t = 0; t < Tt; ++t) {
        const int rb = t & 1, wb = rb ^ 1;   // rb buffer holds h^(t-1)
        const unsigned short* hbase_hi = hg_hi + (size_t)(rb * NXCD + xcd) * NB * Hh;
        const unsigned short* hbase_lo = hg_lo + (size_t)(rb * NXCD + xcd) * NB * Hh;

        // ---- B: GEMM, gate wv, B fragments direct from global (XCD L2) ----
        f32x4 a0 = { 0.f, 0.f, 0.f, 0.f };
        f32x4 a1 = { 0.f, 0.f, 0.f, 0.f };
        f32x4 a2 = { 0.f, 0.f, 0.f, 0.f };
        if (t > 0) {
            const unsigned short* ph = hbase_hi + (size_t)frow * Hh + kgrp * 8;
            const unsigned short* pl = hbase_lo + (size_t)frow * Hh + kgrp * 8;
            #pragma unroll
            for (int kk = 0; kk < 16; ++kk) {
                const bf16x8 bhi = *(const bf16x8*)(ph + kk * 32);
                const bf16x8 blo = *(const bf16x8*)(pl + kk * 32);
                a0 = __builtin_amdgcn_mfma_f32_16x16x32_bf16(wahi[kk], bhi, a0, 0, 0, 0);
                a1 = __builtin_amdgcn_mfma_f32_16x16x32_bf16(wahi[kk], blo, a1, 0, 0, 0);
                a2 = __builtin_amdgcn_mfma_f32_16x16x32_bf16(walo[kk], bhi, a2, 0, 0, 0);
            }
        }
        // C layout: col(lane&15)=batch, row=(lane>>4)*4+reg = unit
        #pragma unroll
        for (int r = 0; r < 4; ++r)
            gbuf[(wv * 16 + kgrp * 4 + r) * 20 + frow] = a0[r] + a1[r] + a2[r];

        // ---- owner (wave 1): out(t-1) BEFORE this block's flag store, so no
        // peer can reach step t+1's h-write (which reuses buffer rb) first ----
        if (t > 0 && wv == 1 && owner)
            emit_out(t - 1, hbase_hi, hbase_lo);

        const float xv = x[(size_t)gb * Tt + t];
        __syncthreads();                 // gbuf ready for phase C

        // ---- C: LSTM elementwise, write h^(t) hi/lo (plain -> XCD L2) ----
        {
            const float gi = gbuf[(0 * 16 + u) * 20 + b_] + xv * wih_r[0] + bias_r[0];
            const float gf = gbuf[(1 * 16 + u) * 20 + b_] + xv * wih_r[1] + bias_r[1];
            const float gg = gbuf[(2 * 16 + u) * 20 + b_] + xv * wih_r[2] + bias_r[2];
            const float go = gbuf[(3 * 16 + u) * 20 + b_] + xv * wih_r[3] + bias_r[3];
            creg = fsig(gf) * creg + fsig(gi) * ftanh(gg);
            const float hnew = fsig(go) * ftanh(creg);
            const unsigned short hb2 = f2bf(hnew);
            const unsigned short lb2 = f2bf(hnew - bf2f(hb2));
            const size_t hoff = ((size_t)(wb * NXCD + xcd) * NB + b_) * Hh + gj;
            hg_hi[hoff] = hb2;
            hg_lo[hoff] = lb2;
        }
        __syncthreads();   // vmcnt(0) drained: h^(t) visible in XCD L2

        // ---- D: plain-store flag (ordered after the drain) ----
        if (tid == 0)
            *(volatile int*)(flags + fbase + rank) = t + 1;

        // ---- E: lanes 0-31 poll flags; buffer_inv per round (PROVEN form) ----
        if (tid < 32) {
            const volatile int* fl = (const volatile int*)(flags + fbase + tid);
            int v = *fl;
            while (__any(v < t + 1)) {
                __builtin_amdgcn_s_sleep(1);
                asm volatile("buffer_inv\n\ts_waitcnt vmcnt(0)" ::: "memory");
                v = *fl;
            }
            // final L1 invalidate: peers' h (in shared XCD L2) becomes visible
            asm volatile("buffer_inv\n\ts_waitcnt vmcnt(0)" ::: "memory");
        }
        __syncthreads();   // block released with clean L1
    }

    // ---- epilogue: out(Tt-1) from h^(Tt-1) (buffer Tt&1), post final poll ----
    if (wv == 1 && owner) {
        const int rbF = Tt & 1;
        emit_out(Tt - 1,
                 hg_hi + (size_t)(rbF * NXCD + xcd) * NB * Hh,
                 hg_lo + (size_t)(rbF * NXCD + xcd) * NB * Hh);
    }
}

extern "C" void kernel_launch(void* const* d_in, const int* in_sizes, int n_in,
                              void* d_out, int out_size, void* d_ws, size_t ws_size,
                              hipStream_t stream)
{
    const float* xp  = (const float*)d_in[0];
    const float* wih = (const float*)d_in[1];
    const float* whh = (const float*)d_in[2];
    const float* bih = (const float*)d_in[3];
    const float* bhh = (const float*)d_in[4];
    const float* wt  = (const float*)d_in[5];
    const float* wfc = (const float*)d_in[6];
    const float* bfc = (const float*)d_in[7];
    float* outp = (float*)d_out;
    float* ws   = (float*)d_ws;

    // zero flags + rank counters each call (graph-capturable)
    (void)hipMemsetAsync(d_ws, 0, 4096, stream);

    hipLaunchKernelGGL(lstm_fused, dim3(GRID), dim3(THREADS), 0, stream,
                       xp, wih, whh, bih, bhh, wt, wfc, bfc, outp, ws);
}

// Round 17
// 6477.505 us; speedup vs baseline: 1.1863x; 1.1863x over previous
//
#include <hip/hip_runtime.h>
#include <math.h>

typedef __attribute__((ext_vector_type(8))) short bf16x8;   // 8 bf16 (4 VGPR)
typedef __attribute__((ext_vector_type(4))) float f32x4;    // MFMA C/D

static constexpr int Tt = 1024;
static constexpr int Hh = 512;
static constexpr int Cc = 10;

static constexpr int NXCD = 8;       // XCDs; each runs an independent group
static constexpr int BPX  = 32;      // blocks (CUs) per XCD
static constexpr int UPB  = 16;      // hidden units per block (64 gate rows)
static constexpr int NB   = 16;      // batch rows per XCD (8*16 = 128)
static constexpr int THREADS = 256;  // 4 waves, wave = gate
static constexpr int GRID = 256;     // 1 block per CU (133 KB LDS forces it)

// ws bytes: [0,1024) flags[8][32] | [1024,2048) rank counters | pad
//           [4096, +256KB) h_hi[2][8][16][512] bf16 | then h_lo 256KB
static constexpr size_t WS_HHI_B = 4096;
static constexpr size_t WS_HLO_B = 4096 + 262144;

__device__ __forceinline__ unsigned short f2bf(float f) {
    unsigned u = __builtin_bit_cast(unsigned, f);
    return (unsigned short)((u + 0x7FFFu + ((u >> 16) & 1u)) >> 16);   // RNE
}
__device__ __forceinline__ float bf2f(unsigned short h) {
    unsigned u = ((unsigned)h) << 16;
    return __builtin_bit_cast(float, u);
}
__device__ __forceinline__ float dot4(float4 a, float4 b) {
    return a.x * b.x + a.y * b.y + a.z * b.z + a.w * b.w;
}
__device__ __forceinline__ float fsig(float x) {
    const float e = __builtin_amdgcn_exp2f(x * -1.44269504f);
    return __builtin_amdgcn_rcpf(1.0f + e);
}
__device__ __forceinline__ float ftanh(float x) {
    const float e = __builtin_amdgcn_exp2f(x * -2.88539008f);
    return 2.0f * __builtin_amdgcn_rcpf(1.0f + e) - 1.0f;
}

__global__ __launch_bounds__(THREADS, 1)
void lstm_fused(const float* __restrict__ x,
                const float* __restrict__ w_ih,
                const float* __restrict__ w_hh,
                const float* __restrict__ b_ih,
                const float* __restrict__ b_hh,
                const float* __restrict__ w_t,
                const float* __restrict__ w_fc,
                const float* __restrict__ b_fc,
                float* __restrict__ out,
                float* __restrict__ ws)
{
    const int tid  = threadIdx.x;
    const int lane = tid & 63;
    const int wv   = tid >> 6;          // 0..3: wave = gate
    const int frow = lane & 15;         // A row / B batch col
    const int kgrp = lane >> 4;         // 8-elem K group within a 32-K step

    int* flags    = (int*)ws;                 // [xcd*32 + rank]
    int* counters = (int*)ws + 256;           // init-time rank claim
    unsigned short* hg_hi = (unsigned short*)((char*)ws + WS_HHI_B);
    unsigned short* hg_lo = (unsigned short*)((char*)ws + WS_HLO_B);

    // LDS: W-hi 64K + W-lo 64K + gbuf 5K = 133 KB -> 1 block/CU guaranteed
    __shared__ __align__(16) short wls_hi[64 * 512];
    __shared__ __align__(16) short wls_lo[64 * 512];
    __shared__ __align__(16) float gbuf[64 * 20];     // [gaterow][batch]
    int* xchg = (int*)wls_hi;                 // init-time only (dead until preload)

    // ---- discover physical XCD, claim a rank ----
    if (tid == 0) {
        int xr;
        asm volatile("s_getreg_b32 %0, hwreg(20, 0, 32)" : "=s"(xr));
        const int xcd = xr & 7;
        xchg[0] = xcd;
        xchg[1] = atomicAdd(&counters[xcd * 32], 1) & 31;
    }
    __syncthreads();
    const int xcd  = xchg[0];
    const int rank = xchg[1];
    __syncthreads();                          // reads done before wls_hi reuse
    const int fbase = xcd * BPX;

    // ---- preload + split w_hh slice into bf16 hi/lo LDS, XOR-swizzled ----
    // (layout + swizzle verified end-to-end in rounds 9/10)
    {
        #pragma unroll
        for (int it = 0; it < 16; ++it) {
            const int idx = it * 256 + tid;        // [0,4096): lr(64) x kg(64)
            const int lr = idx >> 6, kg = idx & 63;
            const int grow = (lr >> 4) * Hh + rank * UPB + (lr & 15);
            const float4* src = (const float4*)(w_hh + (size_t)grow * Hh + kg * 8);
            const float4 f0 = src[0], f1 = src[1];
            const float f[8] = { f0.x, f0.y, f0.z, f0.w, f1.x, f1.y, f1.z, f1.w };
            bf16x8 vhi, vlo;
            #pragma unroll
            for (int j = 0; j < 8; ++j) {
                const unsigned short hb = f2bf(f[j]);
                vhi[j] = (short)hb;
                vlo[j] = (short)f2bf(f[j] - bf2f(hb));
            }
            const int off = (lr * 1024 + kg * 16) ^ ((lr & 7) << 4);
            *(bf16x8*)((char*)wls_hi + off) = vhi;
            *(bf16x8*)((char*)wls_lo + off) = vlo;
        }
    }
    __syncthreads();                          // W resident before first GEMM

    // ---- elementwise role: thread -> (u, b) ----
    const int u  = tid & 15;
    const int b_ = tid >> 4;                 // 0..15
    const int gj = rank * UPB + u;
    const int gb = xcd * NB + b_;
    float wih_r[4], bias_r[4];
    #pragma unroll
    for (int g = 0; g < 4; ++g) {
        wih_r[g]  = w_ih[g * Hh + gj];
        bias_r[g] = b_ih[g * Hh + gj] + b_hh[g * Hh + gj];
    }
    float creg = 0.0f;

    // ---- owner role (wave 1, ranks 0..15): one batch row's output chain ----
    const bool owner = (rank < NB);
    const int  gb_own = xcd * NB + rank;
    float S1w[Cc], S2w[Cc], bfc_r[Cc];
    #pragma unroll
    for (int c = 0; c < Cc; ++c) { S1w[c] = 0.f; S2w[c] = 0.f; bfc_r[c] = b_fc[c]; }

    // MFMA A-fragment addressing (wave wv's 16 gate rows, round-9-verified)
    const int arow  = wv * 16 + frow;
    const int aoff0 = arow * 1024 + (kgrp << 4);
    const int xmask = (lane & 7) << 4;

    // emit out(tprev) from the h buffer at bh/bl (wave-1 lanes, 64-wide)
    auto emit_out = [&](int tprev, const unsigned short* bh, const unsigned short* bl) {
        const size_t rbase = (size_t)rank * Hh + lane * 8;
        const bf16x8 vh = *(const bf16x8*)(bh + rbase);
        const bf16x8 vl = *(const bf16x8*)(bl + rbase);
        float f[8];
        #pragma unroll
        for (int j = 0; j < 8; ++j)
            f[j] = bf2f((unsigned short)vh[j]) + bf2f((unsigned short)vl[j]);
        const float4 hA = make_float4(f[0], f[1], f[2], f[3]);
        const float4 hB = make_float4(f[4], f[5], f[6], f[7]);
        const float4* wt4 = (const float4*)w_t;
        const float4* wf4 = (const float4*)w_fc;
        float r[12];
        r[0] = dot4(hA, wt4[lane * 2])       + dot4(hB, wt4[lane * 2 + 1]);
        r[1] = dot4(hA, wt4[128 + lane * 2]) + dot4(hB, wt4[128 + lane * 2 + 1]);
        #pragma unroll
        for (int c = 0; c < Cc; ++c)
            r[2 + c] = dot4(hA, wf4[c * 128 + lane * 2])
                     + dot4(hB, wf4[c * 128 + lane * 2 + 1]);
        #pragma unroll
        for (int m = 1; m <= 32; m <<= 1)
            #pragma unroll
            for (int k2 = 0; k2 < 12; ++k2)
                r[k2] += __shfl_xor(r[k2], m, 64);
        if (lane == 0) {
            const float a = r[0], b2 = r[1];
            float* po = out + ((size_t)gb_own * Tt + tprev) * Cc;
            #pragma unroll
            for (int c = 0; c < Cc; ++c) {
                const float hw = r[2 + c];
                po[c] = hw + a * S1w[c] + S2w[c] + bfc_r[c];
                S1w[c] += hw;
                S2w[c] += b2 * hw;
            }
        }
    };

    for (int t = 0; t < Tt; ++t) {
        const int rb = t & 1, wb = rb ^ 1;   // rb buffer holds h^(t-1)
        const unsigned short* hbase_hi = hg_hi + (size_t)(rb * NXCD + xcd) * NB * Hh;
        const unsigned short* hbase_lo = hg_lo + (size_t)(rb * NXCD + xcd) * NB * Hh;

        // ---- B: GEMM; A (W) from LDS, B (h) direct from global (XCD L2) ----
        f32x4 a0 = { 0.f, 0.f, 0.f, 0.f };
        f32x4 a1 = { 0.f, 0.f, 0.f, 0.f };
        f32x4 a2 = { 0.f, 0.f, 0.f, 0.f };
        if (t > 0) {
            const unsigned short* ph = hbase_hi + (size_t)frow * Hh + kgrp * 8;
            const unsigned short* pl = hbase_lo + (size_t)frow * Hh + kgrp * 8;
            #pragma unroll
            for (int kk = 0; kk < 16; ++kk) {
                const int ao = (aoff0 + kk * 64) ^ xmask;
                const bf16x8 ahi = *(const bf16x8*)((const char*)wls_hi + ao);
                const bf16x8 alo = *(const bf16x8*)((const char*)wls_lo + ao);
                const bf16x8 bhi = *(const bf16x8*)(ph + kk * 32);
                const bf16x8 blo = *(const bf16x8*)(pl + kk * 32);
                a0 = __builtin_amdgcn_mfma_f32_16x16x32_bf16(ahi, bhi, a0, 0, 0, 0);
                a1 = __builtin_amdgcn_mfma_f32_16x16x32_bf16(ahi, blo, a1, 0, 0, 0);
                a2 = __builtin_amdgcn_mfma_f32_16x16x32_bf16(alo, bhi, a2, 0, 0, 0);
            }
        }
        // C layout: col(lane&15)=batch, row=(lane>>4)*4+reg = unit
        #pragma unroll
        for (int r = 0; r < 4; ++r)
            gbuf[(wv * 16 + kgrp * 4 + r) * 20 + frow] = a0[r] + a1[r] + a2[r];

        // ---- owner (wave 1): out(t-1) BEFORE this block's flag store, so no
        // peer can reach step t+1's h-write (which reuses buffer rb) first ----
        if (t > 0 && wv == 1 && owner)
            emit_out(t - 1, hbase_hi, hbase_lo);

        const float xv = x[(size_t)gb * Tt + t];
        __syncthreads();                 // gbuf ready for phase C

        // ---- C: LSTM elementwise, write h^(t) hi/lo (plain -> XCD L2) ----
        {
            const float gi = gbuf[(0 * 16 + u) * 20 + b_] + xv * wih_r[0] + bias_r[0];
            const float gf = gbuf[(1 * 16 + u) * 20 + b_] + xv * wih_r[1] + bias_r[1];
            const float gg = gbuf[(2 * 16 + u) * 20 + b_] + xv * wih_r[2] + bias_r[2];
            const float go = gbuf[(3 * 16 + u) * 20 + b_] + xv * wih_r[3] + bias_r[3];
            creg = fsig(gf) * creg + fsig(gi) * ftanh(gg);
            const float hnew = fsig(go) * ftanh(creg);
            const unsigned short hb2 = f2bf(hnew);
            const unsigned short lb2 = f2bf(hnew - bf2f(hb2));
            const size_t hoff = ((size_t)(wb * NXCD + xcd) * NB + b_) * Hh + gj;
            hg_hi[hoff] = hb2;
            hg_lo[hoff] = lb2;
        }
        __syncthreads();   // vmcnt(0) drained: h^(t) visible in XCD L2

        // ---- D: plain-store flag (ordered after the drain) ----
        if (tid == 0)
            *(volatile int*)(flags + fbase + rank) = t + 1;

        // ---- E: lanes 0-31 poll flags; buffer_inv per round (PROVEN form) ----
        if (tid < 32) {
            const volatile int* fl = (const volatile int*)(flags + fbase + tid);
            int v = *fl;
            while (__any(v < t + 1)) {
                __builtin_amdgcn_s_sleep(1);
                asm volatile("buffer_inv\n\ts_waitcnt vmcnt(0)" ::: "memory");
                v = *fl;
            }
            // final L1 invalidate: peers' h (in shared XCD L2) becomes visible
            asm volatile("buffer_inv\n\ts_waitcnt vmcnt(0)" ::: "memory");
        }
        __syncthreads();   // block released with clean L1
    }

    // ---- epilogue: out(Tt-1) from h^(Tt-1) (buffer Tt&1), post final poll ----
    if (wv == 1 && owner) {
        const int rbF = Tt & 1;
        emit_out(Tt - 1,
                 hg_hi + (size_t)(rbF * NXCD + xcd) * NB * Hh,
                 hg_lo + (size_t)(rbF * NXCD + xcd) * NB * Hh);
    }
}

extern "C" void kernel_launch(void* const* d_in, const int* in_sizes, int n_in,
                              void* d_out, int out_size, void* d_ws, size_t ws_size,
                              hipStream_t stream)
{
    const float* xp  = (const float*)d_in[0];
    const float* wih = (const float*)d_in[1];
    const float* whh = (const float*)d_in[2];
    const float* bih = (const float*)d_in[3];
    const float* bhh = (const float*)d_in[4];
    const float* wt  = (const float*)d_in[5];
    const float* wfc = (const float*)d_in[6];
    const float* bfc = (const float*)d_in[7];
    float* outp = (float*)d_out;
    float* ws   = (float*)d_ws;

    // zero flags + rank counters each call (graph-capturable)
    (void)hipMemsetAsync(d_ws, 0, 4096, stream);

    hipLaunchKernelGGL(lstm_fused, dim3(GRID), dim3(THREADS), 0, stream,
                       xp, wih, whh, bih, bhh, wt, wfc, bfc, outp, ws);
}

// Round 18
// 5740.072 us; speedup vs baseline: 1.3388x; 1.1285x over previous
//
#include <hip/hip_runtime.h>
#include <math.h>

typedef __attribute__((ext_vector_type(8))) short bf16x8;   // 8 bf16 (4 VGPR)
typedef __attribute__((ext_vector_type(4))) float f32x4;    // MFMA C/D

static constexpr int Tt = 1024;
static constexpr int Hh = 512;
static constexpr int Cc = 10;

static constexpr int NXCD = 8;       // XCDs; each runs an independent group
static constexpr int BPX  = 32;      // blocks (CUs) per XCD
static constexpr int UPB  = 16;      // hidden units per block (64 gate rows)
static constexpr int RPS  = 8;       // batch rows per stream (2 streams/XCD)
static constexpr int THREADS = 256;  // 4 waves; wave = K-quarter
static constexpr int GRID = 256;     // 1 block per CU (148 KB LDS forces it)

// ws bytes: [0,2048) flags[2 streams][8 xcd][32] int
//           [2048,3072) rank counters | [4096, +256KB) h_hi[2][8][16][512] bf16
//           then h_lo 256KB. memset covers [0, 4096+512KB) each call.
static constexpr size_t WS_HHI_B = 4096;
static constexpr size_t WS_HLO_B = 4096 + 262144;
static constexpr size_t WS_ZERO_B = 4096 + 524288;   // memset span

__device__ __forceinline__ unsigned short f2bf(float f) {
    unsigned u = __builtin_bit_cast(unsigned, f);
    return (unsigned short)((u + 0x7FFFu + ((u >> 16) & 1u)) >> 16);   // RNE
}
__device__ __forceinline__ float bf2f(unsigned short h) {
    unsigned u = ((unsigned)h) << 16;
    return __builtin_bit_cast(float, u);
}
__device__ __forceinline__ float dot4(float4 a, float4 b) {
    return a.x * b.x + a.y * b.y + a.z * b.z + a.w * b.w;
}
__device__ __forceinline__ float fsig(float x) {
    const float e = __builtin_amdgcn_exp2f(x * -1.44269504f);
    return __builtin_amdgcn_rcpf(1.0f + e);
}
__device__ __forceinline__ float ftanh(float x) {
    const float e = __builtin_amdgcn_exp2f(x * -2.88539008f);
    return 2.0f * __builtin_amdgcn_rcpf(1.0f + e) - 1.0f;
}

__global__ __launch_bounds__(THREADS, 1)
void lstm_fused(const float* __restrict__ x,
                const float* __restrict__ w_ih,
                const float* __restrict__ w_hh,
                const float* __restrict__ b_ih,
                const float* __restrict__ b_hh,
                const float* __restrict__ w_t,
                const float* __restrict__ w_fc,
                const float* __restrict__ b_fc,
                float* __restrict__ out,
                float* __restrict__ ws)
{
    const int tid  = threadIdx.x;
    const int lane = tid & 63;
    const int wv   = tid >> 6;          // wave = K-quarter (kk in [wv*4, wv*4+4))
    const int frow = lane & 15;         // A row within 16-tile / B batch col
    const int kgrp = lane >> 4;         // 8-elem K group within a 32-K step

    int* flags0   = (int*)ws;                 // stream 0: [xcd*32 + rank]
    int* flags1   = (int*)ws + 256;           // stream 1
    int* counters = (int*)ws + 512;           // init-time rank claim
    unsigned short* hg_hi = (unsigned short*)((char*)ws + WS_HHI_B);
    unsigned short* hg_lo = (unsigned short*)((char*)ws + WS_HLO_B);

    // LDS: W-hi 64K + W-lo 64K + gbuf 20K = 148 KB -> 1 block/CU guaranteed
    __shared__ __align__(16) short wls_hi[64 * 512];
    __shared__ __align__(16) short wls_lo[64 * 512];
    __shared__ __align__(16) float gbuf[4 * 64 * 20];  // [quarter][gaterow][col]
    int* xchg = (int*)wls_hi;                 // init-time only

    // ---- discover physical XCD, claim a rank ----
    if (tid == 0) {
        int xr;
        asm volatile("s_getreg_b32 %0, hwreg(20, 0, 32)" : "=s"(xr));
        const int xcd = xr & 7;
        xchg[0] = xcd;
        xchg[1] = atomicAdd(&counters[xcd * 32], 1) & 31;
    }
    __syncthreads();
    const int xcd  = xchg[0];
    const int rank = xchg[1];
    __syncthreads();                          // reads done before wls_hi reuse
    const int fbase = xcd * BPX;

    // ---- preload + split w_hh slice into bf16 hi/lo LDS, XOR-swizzled ----
    // (layout + swizzle verified end-to-end rounds 9/10/17)
    {
        #pragma unroll
        for (int it = 0; it < 16; ++it) {
            const int idx = it * 256 + tid;        // [0,4096): lr(64) x kg(64)
            const int lr = idx >> 6, kg = idx & 63;
            const int grow = (lr >> 4) * Hh + rank * UPB + (lr & 15);
            const float4* src = (const float4*)(w_hh + (size_t)grow * Hh + kg * 8);
            const float4 f0 = src[0], f1 = src[1];
            const float f[8] = { f0.x, f0.y, f0.z, f0.w, f1.x, f1.y, f1.z, f1.w };
            bf16x8 vhi, vlo;
            #pragma unroll
            for (int j = 0; j < 8; ++j) {
                const unsigned short hb = f2bf(f[j]);
                vhi[j] = (short)hb;
                vlo[j] = (short)f2bf(f[j] - bf2f(hb));
            }
            const int off = (lr * 1024 + kg * 16) ^ ((lr & 7) << 4);
            *(bf16x8*)((char*)wls_hi + off) = vhi;
            *(bf16x8*)((char*)wls_lo + off) = vlo;
        }
    }

    // ---- elementwise role (tid < 128): thread -> (u, b) of the active stream ----
    const int u  = tid & 15;
    const int b_ = tid >> 4;                 // 0..7 for tid<128
    const int gj = rank * UPB + u;
    float wih_r[4], bias_r[4];
    #pragma unroll
    for (int g = 0; g < 4; ++g) {
        wih_r[g]  = w_ih[g * Hh + gj];
        bias_r[g] = b_ih[g * Hh + gj] + b_hh[g * Hh + gj];
    }
    float creg0 = 0.0f, creg1 = 0.0f;        // cell state, stream 0 / stream 1

    // ---- owner role: rank r (<16) owns batch row xcd*16 + r; stream = r>>3 ----
    const bool owner  = (rank < 16);
    const int  ostrm  = rank >> 3;
    const int  gb_own = xcd * 16 + rank;
    float S1w[Cc], S2w[Cc], bfc_r[Cc];
    #pragma unroll
    for (int c = 0; c < Cc; ++c) { S1w[c] = 0.f; S2w[c] = 0.f; bfc_r[c] = b_fc[c]; }

    const int xmask = (lane & 7) << 4;

    // emit out(tprev_ref) reading h buffer bh/bl (wave-3 lanes of owner blocks)
    auto emit_out = [&](int tprev, const unsigned short* bh, const unsigned short* bl) {
        const size_t rbase = (size_t)rank * Hh + lane * 8;   // row = rank (0..15)
        const bf16x8 vh = *(const bf16x8*)(bh + rbase);
        const bf16x8 vl = *(const bf16x8*)(bl + rbase);
        float f[8];
        #pragma unroll
        for (int j = 0; j < 8; ++j)
            f[j] = bf2f((unsigned short)vh[j]) + bf2f((unsigned short)vl[j]);
        const float4 hA = make_float4(f[0], f[1], f[2], f[3]);
        const float4 hB = make_float4(f[4], f[5], f[6], f[7]);
        const float4* wt4 = (const float4*)w_t;
        const float4* wf4 = (const float4*)w_fc;
        float r[12];
        r[0] = dot4(hA, wt4[lane * 2])       + dot4(hB, wt4[lane * 2 + 1]);
        r[1] = dot4(hA, wt4[128 + lane * 2]) + dot4(hB, wt4[128 + lane * 2 + 1]);
        #pragma unroll
        for (int c = 0; c < Cc; ++c)
            r[2 + c] = dot4(hA, wf4[c * 128 + lane * 2])
                     + dot4(hB, wf4[c * 128 + lane * 2 + 1]);
        #pragma unroll
        for (int m = 1; m <= 32; m <<= 1)
            #pragma unroll
            for (int k2 = 0; k2 < 12; ++k2)
                r[k2] += __shfl_xor(r[k2], m, 64);
        if (lane == 0) {
            const float a = r[0], b2 = r[1];
            float* po = out + ((size_t)gb_own * Tt + tprev) * Cc;
            #pragma unroll
            for (int c = 0; c < Cc; ++c) {
                const float hw = r[2 + c];
                po[c] = hw + a * S1w[c] + S2w[c] + bfc_r[c];
                S1w[c] += hw;
                S2w[c] += b2 * hw;
            }
        }
    };

    // poll helper: lanes<32 wait flags_s[*] >= target (proven buffer_inv form)
    auto poll = [&](int* fl_arr, int target) {
        if (tid < 32) {
            const volatile int* fl = (const volatile int*)(fl_arr + fbase + tid);
            int v = *fl;
            while (__any(v < target)) {
                __builtin_amdgcn_s_sleep(1);
                asm volatile("buffer_inv\n\ts_waitcnt vmcnt(0)" ::: "memory");
                v = *fl;
            }
            asm volatile("buffer_inv\n\ts_waitcnt vmcnt(0)" ::: "memory");
        }
    };

    // one stream half-step: poll(t-1) -> GEMM -> owner -> elementwise -> flag(t)
    auto half_step = [&](int s, int t, int* fl_arr, float& creg) {
        const int rb = (t - 1) & 1, wb = t & 1;
        const unsigned short* hbhi = hg_hi + (size_t)(rb * NXCD + xcd) * 16 * Hh;
        const unsigned short* hblo = hg_lo + (size_t)(rb * NXCD + xcd) * 16 * Hh;

        poll(fl_arr, t - 1);
        __syncthreads();                       // (1) release: h_s(t-1) visible

        // GEMM: wave = K-quarter wv; all 4 gates; B dedup'd per wave from L2
        f32x4 acc[4][3];
        #pragma unroll
        for (int g = 0; g < 4; ++g)
            #pragma unroll
            for (int p = 0; p < 3; ++p)
                acc[g][p] = f32x4{ 0.f, 0.f, 0.f, 0.f };
        {
            const int row16 = s * RPS + (frow & 7);
            const unsigned short* ph = hbhi + (size_t)row16 * Hh + kgrp * 8;
            const unsigned short* pl = hblo + (size_t)row16 * Hh + kgrp * 8;
            #pragma unroll
            for (int j = 0; j < 4; ++j) {
                const int kk = wv * 4 + j;
                const bf16x8 bhi = *(const bf16x8*)(ph + kk * 32);
                const bf16x8 blo = *(const bf16x8*)(pl + kk * 32);
                #pragma unroll
                for (int g = 0; g < 4; ++g) {
                    const int ao = ((g * 16 + frow) * 1024 + (kgrp << 4) + kk * 64) ^ xmask;
                    const bf16x8 ahi = *(const bf16x8*)((const char*)wls_hi + ao);
                    const bf16x8 alo = *(const bf16x8*)((const char*)wls_lo + ao);
                    acc[g][0] = __builtin_amdgcn_mfma_f32_16x16x32_bf16(ahi, bhi, acc[g][0], 0, 0, 0);
                    acc[g][1] = __builtin_amdgcn_mfma_f32_16x16x32_bf16(ahi, blo, acc[g][1], 0, 0, 0);
                    acc[g][2] = __builtin_amdgcn_mfma_f32_16x16x32_bf16(alo, bhi, acc[g][2], 0, 0, 0);
                }
            }
        }
        // C layout: col=lane&15 (batch, cols>=8 dup), row=(lane>>4)*4+reg
        #pragma unroll
        for (int g = 0; g < 4; ++g)
            #pragma unroll
            for (int r = 0; r < 4; ++r)
                gbuf[(wv * 64 + g * 16 + kgrp * 4 + r) * 20 + frow] =
                    acc[g][0][r] + acc[g][1][r] + acc[g][2][r];

        // owner (wave 3, matching stream): out(t-2) from h(t-1), pre-flag-store
        if (t >= 2 && wv == 3 && owner && ostrm == s)
            emit_out(t - 2, hbhi, hblo);

        float xv = 0.f;
        if (tid < 128) xv = x[(size_t)(xcd * 16 + s * RPS + b_) * Tt + (t - 1)];
        __syncthreads();                       // (2) gbuf ready; h(t-1) reads done

        if (tid < 128) {
            float gs[4];
            #pragma unroll
            for (int g = 0; g < 4; ++g) {
                const int base = (g * 16 + u) * 20 + b_;
                gs[g] = gbuf[base] + gbuf[base + 1280]
                      + gbuf[base + 2560] + gbuf[base + 3840];
            }
            const float gi = gs[0] + xv * wih_r[0] + bias_r[0];
            const float gf = gs[1] + xv * wih_r[1] + bias_r[1];
            const float gg = gs[2] + xv * wih_r[2] + bias_r[2];
            const float go = gs[3] + xv * wih_r[3] + bias_r[3];
            creg = fsig(gf) * creg + fsig(gi) * ftanh(gg);
            const float hnew = fsig(go) * ftanh(creg);
            const unsigned short hb2 = f2bf(hnew);
            const unsigned short lb2 = f2bf(hnew - bf2f(hb2));
            const size_t hoff = ((size_t)(wb * NXCD + xcd) * 16 + s * RPS + b_) * Hh + gj;
            hg_hi[hoff] = hb2;
            hg_lo[hoff] = lb2;
        }
        __syncthreads();                       // (3) drain: h(t) visible in L2

        if (tid == 0)
            *(volatile int*)(fl_arr + fbase + rank) = t;
    };

    for (int t = 1; t <= Tt; ++t) {
        half_step(0, t, flags0, creg0);        // stream 0
        half_step(1, t, flags1, creg1);        // stream 1 (hides S0 propagation)
    }

    // ---- epilogue: poll both streams to Tt, emit out(Tt-1) from h(Tt) ----
    poll(flags0, Tt);
    poll(flags1, Tt);
    __syncthreads();
    if (wv == 3 && owner) {
        const int rbF = Tt & 1;
        emit_out(Tt - 1,
                 hg_hi + (size_t)(rbF * NXCD + xcd) * 16 * Hh,
                 hg_lo + (size_t)(rbF * NXCD + xcd) * 16 * Hh);
    }
}

extern "C" void kernel_launch(void* const* d_in, const int* in_sizes, int n_in,
                              void* d_out, int out_size, void* d_ws, size_t ws_size,
                              hipStream_t stream)
{
    const float* xp  = (const float*)d_in[0];
    const float* wih = (const float*)d_in[1];
    const float* whh = (const float*)d_in[2];
    const float* bih = (const float*)d_in[3];
    const float* bhh = (const float*)d_in[4];
    const float* wt  = (const float*)d_in[5];
    const float* wfc = (const float*)d_in[6];
    const float* bfc = (const float*)d_in[7];
    float* outp = (float*)d_out;
    float* ws   = (float*)d_ws;

    // zero flags + counters + BOTH h buffers (h(0)=0; deterministic per call)
    (void)hipMemsetAsync(d_ws, 0, WS_ZERO_B, stream);

    hipLaunchKernelGGL(lstm_fused, dim3(GRID), dim3(THREADS), 0, stream,
                       xp, wih, whh, bih, bhh, wt, wfc, bfc, outp, ws);
}